// Round 6
// baseline (13.949 us; speedup 1.0000x reference)
//
#include <hip/hip_runtime.h>
#include <math.h>

#define LC  32
#define QC  4096
#define WC  3972
#define NU  993    // windows per residue class
#define RUN 8      // windows per lane (128 lanes per residue class)

__device__ __forceinline__ int skew(int a) { return a + (a >> 6); }

__global__ __launch_bounds__(512, 4) void feature_kernel(
    const float* __restrict__ x,          // (B, C, Q)
    const float* __restrict__ shp,        // (L,)
    const float* __restrict__ posMap,     // (W,)
    const float* __restrict__ posSlope_p, // scalar
    float* __restrict__ out,              // (B,)
    int C)
{
    __shared__ float sx[4352];   // skewed x row (staged region: skew(0..4095))
    __shared__ float smin[8];

    const int tid   = threadIdx.x;
    const int b     = blockIdx.x;
    const int lane  = tid & 63;
    const int wv_id = tid >> 6;                    // wave 0..7
    const int r     = wv_id & 3;                   // residue class
    const int gl    = ((wv_id >> 2) << 6) | lane;  // lane-in-residue 0..127
    const int u0    = gl * RUN;
    const int w0    = r + 4 * u0;

    // ---- issue position-weight loads first (L1/L2-resident 16 KB; latency
    //      hides under the x staging below) ----
    const float ps = posSlope_p[0];
    float pwv[RUN];
    #pragma unroll
    for (int k = 0; k < RUN; ++k) {
        int w  = w0 + 4 * k;
        int wi = (w < WC) ? w : (WC - 1);
        pwv[k] = posMap[wi];
    }

    // ---- stage x row into skewed LDS (1024 float4s over 512 threads) ----
    {
        const float4* xr4 = reinterpret_cast<const float4*>(x + ((size_t)b * C + 3) * QC);
        #pragma unroll
        for (int i = 0; i < 2; ++i) {
            int a4 = tid + i * 512;
            float4 v = xr4[a4];
            int s = skew(a4 * 4);   // float4 never crosses a 64-group
            sx[s] = v.x; sx[s+1] = v.y; sx[s+2] = v.z; sx[s+3] = v.w;
        }
    }

    // elu -> weight, while stores retire
    #pragma unroll
    for (int k = 0; k < RUN; ++k) {
        float z = -pwv[k];
        float e = (z > 0.f) ? z : (__expf(z) - 1.f);
        pwv[k] = fmaf(ps, e, 2.0f);
    }

    // shapelet (uniform addresses) + moments
    float sreg[LC];
    #pragma unroll
    for (int j = 0; j < LC; ++j) sreg[j] = shp[j];
    float Ssum = 0.f, S2 = 0.f;
    #pragma unroll
    for (int j = 0; j < LC; ++j) { Ssum += sreg[j]; S2 = fmaf(sreg[j], sreg[j], S2); }
    // d = C0 - (dot - m*Ssum)*inv/16, since (sq/L - m^2)*inv^2 == 31/32 with inv=rsqrt(var)
    const float C0 = S2 * (1.0f / 32.0f) + 31.0f / 32.0f;

    __syncthreads();

    // ---- fill rotating register buffer ----
    float buf[32];
    #pragma unroll
    for (int p = 0; p < 32; ++p)
        buf[p] = sx[skew(w0 + 4 * p)];

    float a0=0,a1=0,a2=0,a3=0, q0=0,q1=0,q2=0,q3=0;
    #pragma unroll
    for (int p = 0; p < 32; p += 4) {
        a0 += buf[p];   q0 = fmaf(buf[p],   buf[p],   q0);
        a1 += buf[p+1]; q1 = fmaf(buf[p+1], buf[p+1], q1);
        a2 += buf[p+2]; q2 = fmaf(buf[p+2], buf[p+2], q2);
        a3 += buf[p+3]; q3 = fmaf(buf[p+3], buf[p+3], q3);
    }
    float sum = (a0+a1)+(a2+a3);
    float sq  = (q0+q1)+(q2+q3);

    float best = INFINITY;

    #pragma unroll
    for (int k = 0; k < RUN; ++k) {
        if (k > 0) {
            int slot = (k + 31) & 31;
            float oldv = buf[slot];
            float newv = sx[skew(w0 + 4 * (k + 31))];
            sum += newv - oldv;
            sq  += fmaf(newv, newv, -(oldv * oldv));
            buf[slot] = newv;
        }
        float d0=0,d1=0,d2=0,d3=0;
        #pragma unroll
        for (int j = 0; j < LC; j += 4) {
            d0 = fmaf(sreg[j],   buf[(k+j)   & 31], d0);
            d1 = fmaf(sreg[j+1], buf[(k+j+1) & 31], d1);
            d2 = fmaf(sreg[j+2], buf[(k+j+2) & 31], d2);
            d3 = fmaf(sreg[j+3], buf[(k+j+3) & 31], d3);
        }
        float dot = (d0+d1)+(d2+d3);

        float m   = sum * (1.0f / 32.0f);
        float var = (sq - 32.0f * m * m) * (1.0f / 31.0f);
        var = fmaxf(var, 1e-24f);
        float inv = __builtin_amdgcn_rsqf(var);
        float t   = fmaf(-m, Ssum, dot);                  // dot - m*Ssum
        float d   = fmaf(-t * (1.0f / 16.0f), inv, C0);   // |t|*inv bounded (Cauchy-Schwarz)
        float f   = ((u0 + k) < NU) ? d * pwv[k] : INFINITY;
        best = fminf(best, f);
    }

    // ---- block min reduction ----
    #pragma unroll
    for (int off = 32; off > 0; off >>= 1)
        best = fminf(best, __shfl_down(best, off, 64));
    if (lane == 0) smin[wv_id] = best;
    __syncthreads();
    if (tid == 0) {
        float m0 = fminf(fminf(smin[0], smin[1]), fminf(smin[2], smin[3]));
        float m1 = fminf(fminf(smin[4], smin[5]), fminf(smin[6], smin[7]));
        out[b] = fmaxf(fminf(m0, m1), 0.0f);
    }
}

extern "C" void kernel_launch(void* const* d_in, const int* in_sizes, int n_in,
                              void* d_out, int out_size, void* d_ws, size_t ws_size,
                              hipStream_t stream) {
    const float* x        = (const float*)d_in[0];
    const float* shp      = (const float*)d_in[1];
    const float* posMap   = (const float*)d_in[2];
    const float* posSlope = (const float*)d_in[3];
    float* out = (float*)d_out;

    const int C = 8;
    const int B = in_sizes[0] / (C * QC);   // 512

    feature_kernel<<<B, 512, 0, stream>>>(x, shp, posMap, posSlope, out, C);
}

// Round 7
// 11.312 us; speedup vs baseline: 1.2330x; 1.2330x over previous
//
#include <hip/hip_runtime.h>
#include <math.h>

#define LC  32
#define QC  4096
#define WC  3972
#define NU  993    // windows per residue class (WC/4)
#define RUN 8      // windows per lane (128 lanes per residue class)

__device__ __forceinline__ int skew(int a) { return a + (a >> 6); }

__global__ __launch_bounds__(512, 4) void feature_kernel(
    const float* __restrict__ x,          // (B, C, Q)
    const float* __restrict__ shp,        // (L,)
    const float* __restrict__ posMap,     // (W,)
    const float* __restrict__ posSlope_p, // scalar
    float* __restrict__ out,              // (B,)
    int C)
{
    __shared__ float sx[4352];   // skewed x row
    __shared__ float sw[4160];   // skewed position weights (tail garbage, masked)
    __shared__ float smin[8];

    const int tid   = threadIdx.x;
    const int b     = blockIdx.x;
    const float* __restrict__ xr = x + ((size_t)b * C + 3) * QC;

    // ---- stage x row into skewed LDS (coalesced float4) ----
    {
        const float4* xr4 = reinterpret_cast<const float4*>(xr);
        #pragma unroll
        for (int i = 0; i < 2; ++i) {
            int a4 = tid + i * 512;
            float4 v = xr4[a4];
            int s = skew(a4 * 4);       // float4 never crosses a 64-group
            sx[s] = v.x; sx[s+1] = v.y; sx[s+2] = v.z; sx[s+3] = v.w;
        }
    }
    // ---- stage position weights w(pos)=posSlope*elu(-posMap)+2 (coalesced) ----
    {
        const float ps = posSlope_p[0];
        const float4* pm4 = reinterpret_cast<const float4*>(posMap);
        #pragma unroll
        for (int i = 0; i < 2; ++i) {
            int a4 = tid + i * 512;
            if (a4 < NU) {              // WC/4 == NU float4 chunks
                float4 z = pm4[a4];
                float e0 = (-z.x > 0.f) ? -z.x : (__expf(-z.x) - 1.f);
                float e1 = (-z.y > 0.f) ? -z.y : (__expf(-z.y) - 1.f);
                float e2 = (-z.z > 0.f) ? -z.z : (__expf(-z.z) - 1.f);
                float e3 = (-z.w > 0.f) ? -z.w : (__expf(-z.w) - 1.f);
                int s = skew(a4 * 4);
                sw[s]   = fmaf(ps, e0, 2.0f);
                sw[s+1] = fmaf(ps, e1, 2.0f);
                sw[s+2] = fmaf(ps, e2, 2.0f);
                sw[s+3] = fmaf(ps, e3, 2.0f);
            }
        }
    }

    // shapelet (uniform addresses -> scalar path) + moments
    float sreg[LC];
    #pragma unroll
    for (int j = 0; j < LC; ++j) sreg[j] = shp[j];
    float Ssum = 0.f, S2 = 0.f;
    #pragma unroll
    for (int j = 0; j < LC; ++j) { Ssum += sreg[j]; S2 = fmaf(sreg[j], sreg[j], S2); }
    // Collapsed epilogue constant: (sq/L - m^2)*inv^2 == 31/32 with inv=rsqrt(var)
    const float C0 = S2 * (1.0f / 32.0f) + 31.0f / 32.0f;

    __syncthreads();

    const int lane  = tid & 63;
    const int wv_id = tid >> 6;                    // wave 0..7
    const int r     = wv_id & 3;                   // residue class
    const int gl    = ((wv_id >> 2) << 6) | lane;  // lane-in-residue 0..127
    const int u0    = gl * RUN;
    const int w0    = r + 4 * u0;

    // ---- fill rotating register buffer ----
    float buf[32];
    #pragma unroll
    for (int p = 0; p < 32; ++p)
        buf[p] = sx[skew(w0 + 4 * p)];

    float a0=0,a1=0,a2=0,a3=0, q0=0,q1=0,q2=0,q3=0;
    #pragma unroll
    for (int p = 0; p < 32; p += 4) {
        a0 += buf[p];   q0 = fmaf(buf[p],   buf[p],   q0);
        a1 += buf[p+1]; q1 = fmaf(buf[p+1], buf[p+1], q1);
        a2 += buf[p+2]; q2 = fmaf(buf[p+2], buf[p+2], q2);
        a3 += buf[p+3]; q3 = fmaf(buf[p+3], buf[p+3], q3);
    }
    float sum = (a0+a1)+(a2+a3);
    float sq  = (q0+q1)+(q2+q3);

    float best = INFINITY;

    #pragma unroll
    for (int k = 0; k < RUN; ++k) {
        if (k > 0) {
            int slot = (k + 31) & 31;
            float oldv = buf[slot];
            float newv = sx[skew(w0 + 4 * (k + 31))];
            sum += newv - oldv;
            sq  += fmaf(newv, newv, -(oldv * oldv));
            buf[slot] = newv;
        }
        float d0=0,d1=0,d2=0,d3=0;
        #pragma unroll
        for (int j = 0; j < LC; j += 4) {
            d0 = fmaf(sreg[j],   buf[(k+j)   & 31], d0);
            d1 = fmaf(sreg[j+1], buf[(k+j+1) & 31], d1);
            d2 = fmaf(sreg[j+2], buf[(k+j+2) & 31], d2);
            d3 = fmaf(sreg[j+3], buf[(k+j+3) & 31], d3);
        }
        float dot = (d0+d1)+(d2+d3);

        const int  u     = u0 + k;
        const bool valid = u < NU;
        float wvv = sw[skew(r + 4 * u)];   // coalesced-staged, conflict-free read

        float m   = sum * (1.0f / 32.0f);
        float var = (sq - 32.0f * m * m) * (1.0f / 31.0f);
        var = fmaxf(var, 1e-24f);
        float inv = __builtin_amdgcn_rsqf(var);
        float t   = fmaf(-m, Ssum, dot);                  // dot - m*Ssum
        float d   = fmaf(-t * (1.0f / 16.0f), inv, C0);
        float f   = valid ? d * wvv : INFINITY;
        best = fminf(best, f);
    }

    // ---- block min reduction ----
    #pragma unroll
    for (int off = 32; off > 0; off >>= 1)
        best = fminf(best, __shfl_down(best, off, 64));
    if (lane == 0) smin[wv_id] = best;
    __syncthreads();
    if (tid == 0) {
        float m0 = fminf(fminf(smin[0], smin[1]), fminf(smin[2], smin[3]));
        float m1 = fminf(fminf(smin[4], smin[5]), fminf(smin[6], smin[7]));
        out[b] = fmaxf(fminf(m0, m1), 0.0f);
    }
}

extern "C" void kernel_launch(void* const* d_in, const int* in_sizes, int n_in,
                              void* d_out, int out_size, void* d_ws, size_t ws_size,
                              hipStream_t stream) {
    const float* x        = (const float*)d_in[0];
    const float* shp      = (const float*)d_in[1];
    const float* posMap   = (const float*)d_in[2];
    const float* posSlope = (const float*)d_in[3];
    float* out = (float*)d_out;

    const int C = 8;
    const int B = in_sizes[0] / (C * QC);   // 512

    feature_kernel<<<B, 512, 0, stream>>>(x, shp, posMap, posSlope, out, C);
}